// Round 3
// baseline (288.956 us; speedup 1.0000x reference)
//
#include <hip/hip_runtime.h>
#include <hip/hip_bf16.h>

#define SCALE 3.5f
#define TJ 256            // square tile size (points) — quartered for tail reduction
#define THREADS 256       // 4 waves per block
#define NA 4              // A-frags per wave: 4*16 = 64 i-pts; 4 waves = 256
#define EDGE_BLOCKS 256
#define MAGIC 0x13572468  // != 0xAAAAAAAA poison

typedef __attribute__((ext_vector_type(8))) short short8;   // 8 bf16 = 4 VGPRs
typedef __attribute__((ext_vector_type(4))) short short4v;  // 4 bf16 = 2 VGPRs
typedef __attribute__((ext_vector_type(4))) float float4v;

// fp32 -> bf16 round-to-nearest-even (bit trick; inputs finite)
__device__ inline short bfh(float v) {
    union { float f; unsigned u; } x; x.f = v;
    unsigned r = (x.u + 0x7fffu + ((x.u >> 16) & 1u)) >> 16;
    return (short)r;
}
__device__ inline float bff(short s) {
    union { float f; unsigned u; } x; x.u = ((unsigned)(unsigned short)s) << 16;
    return x.f;
}

// LDS layout (short4v entries, 8B each):
#define AHI 0
#define ALO 256
#define BHI 512
#define BLO 768
#define ZZ  1024   // 16 zero entries

// ws: double pZ[nbBlocks] | double pC[EDGE_BLOCKS] | double pS[EDGE_BLOCKS]
//     | int flags[EDGE_BLOCKS + nbBlocks]   (0xAA poison != MAGIC)

__global__ __launch_bounds__(THREADS, 4)
void fused_kernel(const float* __restrict__ emb,
                  const float* __restrict__ p,
                  const int* __restrict__ heads,
                  const int* __restrict__ tails,
                  int e, int n, int nt, int nbBlocks,
                  double* __restrict__ pZ,
                  double* __restrict__ pC,
                  double* __restrict__ pS,
                  int* __restrict__ flags,
                  float* __restrict__ out) {
    const int bid = blockIdx.x;
    const float2* e2 = (const float2*)emb;
    const int lane = threadIdx.x & 63, wid = threadIdx.x >> 6;

    if (bid >= EDGE_BLOCKS && bid < EDGE_BLOCKS + nbBlocks) {
        // ================= n-body tile (Z) via MFMA =================
        // t_ij = 1+|pi-pj|^2 = dot([ai,bi,ci,1],[xj,yj,1,fj]); scaled coords.
        // bf16 hi/lo split both sides, all 4 cross-products kept in K=32:
        //  quad0: A[ahi,bhi,chi,1, alo,blo,clo,0]  B[xh,yh,1,fh, xh,yh,1,fh]
        //  quad1: A[ahi,bhi,chi,1, 0,0,0,0]        B[xl,yl,0,fl, 0,0,0,0]
        //  quad2: A[alo,blo,clo,0, 0,0,0,0]        B[xl,yl,0,fl, 0,0,0,0]
        //  quad3: zeros
        const int b = bid - EDGE_BLOCKS;
        int ti = (int)((2.0f * nt + 1.0f -
                        sqrtf((float)((2 * nt + 1) * (2 * nt + 1) - 8 * b))) * 0.5f);
        while ((ti + 1) * nt - ((ti + 1) * ti) / 2 <= b) ++ti;
        while (ti * nt - (ti * (ti - 1)) / 2 > b) --ti;
        const int tj = ti + (b - (ti * nt - (ti * (ti - 1)) / 2));
        const int ibase = ti * TJ, jbase = tj * TJ;

        __shared__ __align__(16) short4v lds[1040];
        const short ONE = (short)0x3F80;  // bf16 1.0
        for (int k = threadIdx.x; k < TJ; k += THREADS) {
            float2 v = e2[ibase + k];
            float X = v.x * SCALE, Y = v.y * SCALE;
            float A = -2.0f * X, B = -2.0f * Y, C = fmaf(X, X, fmaf(Y, Y, 1.0f));
            short ah = bfh(A), bh = bfh(B), ch = bfh(C);
            lds[AHI + k] = (short4v){ah, bh, ch, ONE};
            lds[ALO + k] = (short4v){bfh(A - bff(ah)), bfh(B - bff(bh)),
                                     bfh(C - bff(ch)), 0};
            float2 u = e2[jbase + k];
            float Xj = u.x * SCALE, Yj = u.y * SCALE, F = fmaf(Xj, Xj, Yj * Yj);
            short xh = bfh(Xj), yh = bfh(Yj), fh = bfh(F);
            lds[BHI + k] = (short4v){xh, yh, ONE, fh};
            lds[BLO + k] = (short4v){bfh(Xj - bff(xh)), bfh(Yj - bff(yh)), 0,
                                     bfh(F - bff(fh))};
        }
        if (threadIdx.x < 16) lds[ZZ + threadIdx.x] = (short4v){0, 0, 0, 0};
        __syncthreads();

        const int m = lane & 15, q = lane >> 4;

        // A-frags: wave wid owns i-points wid*64 + a*16 + m
        short8 afr[NA];
#pragma unroll
        for (int a = 0; a < NA; ++a) {
            const int idx = wid * 64 + a * 16 + m;
            short4v h1 = (q <= 1) ? lds[AHI + idx]
                       : (q == 2) ? lds[ALO + idx] : lds[ZZ + m];
            short4v h2 = (q == 0) ? lds[ALO + idx] : lds[ZZ + m];
            afr[a] = __builtin_shufflevector(h1, h2, 0, 1, 2, 3, 4, 5, 6, 7);
        }

        // B index streams (group-invariant base/step per lane; ZZ stays fixed)
        int bi1 = ((q == 0) ? BHI : (q <= 2) ? BLO : ZZ) + m;
        int bi2 = ((q == 0) ? BHI : ZZ) + m;
        const int st1 = (q <= 2) ? 16 : 0;
        const int st2 = (q == 0) ? 16 : 0;

        const float4v cz = {0.0f, 0.0f, 0.0f, 0.0f};
        float accv = 0.0f;
        for (int g = 0; g < TJ / 16; ++g) {
            short4v h1 = lds[bi1], h2 = lds[bi2];
            bi1 += st1; bi2 += st2;
            short8 bfr = __builtin_shufflevector(h1, h2, 0, 1, 2, 3, 4, 5, 6, 7);
#pragma unroll
            for (int a = 0; a < NA; ++a) {
                float4v D = __builtin_amdgcn_mfma_f32_16x16x32_bf16(afr[a], bfr,
                                                                    cz, 0, 0, 0);
                // 4-way rcp combine: sum 1/t = ((t2+t3)ab + (t0+t1)cd)/(ab*cd)
                float t0 = D[0], t1 = D[1], t2 = D[2], t3 = D[3];
                float ab = t0 * t1, cd = t2 * t3;
                float num = fmaf(t2 + t3, ab, (t0 + t1) * cd);
                accv = fmaf(num, __builtin_amdgcn_rcpf(ab * cd), accv);
            }
        }
#pragma unroll
        for (int off = 32; off > 0; off >>= 1)
            accv += __shfl_down(accv, off, 64);

        __shared__ float nred[THREADS / 64];
        if (lane == 0) nred[wid] = accv;
        __syncthreads();
        if (threadIdx.x == 0) {
            float tot = 0.0f;
#pragma unroll
            for (int w = 0; w < THREADS / 64; ++w) tot += nred[w];
            double val = (ti == tj ? 1.0 : 2.0) * (double)tot;
            __hip_atomic_store(&pZ[b], val, __ATOMIC_RELAXED, __HIP_MEMORY_SCOPE_AGENT);
            __hip_atomic_store(&flags[bid], MAGIC, __ATOMIC_RELEASE,
                               __HIP_MEMORY_SCOPE_AGENT);
        }
    } else if (bid < EDGE_BLOCKS) {
        // ================= edge (attractive + entropy) =================
        const int4* h4 = (const int4*)heads;
        const int4* t4 = (const int4*)tails;
        const float4* p4 = (const float4*)p;
        const int e4 = e >> 2;
        const int stride = EDGE_BLOCKS * THREADS;
        float accC = 0.0f, accS = 0.0f;
        for (int idx = bid * THREADS + threadIdx.x; idx < e4; idx += stride) {
            int4 h = h4[idx];
            int4 t = t4[idx];
            float4 pv = p4[idx];
            {
                float2 a = e2[h.x], b = e2[t.x];
                float dx = a.x - b.x, dy = a.y - b.y;
                float sq = fmaf(dx, dx, dy * dy) * (SCALE * SCALE);
                accC += pv.x * __logf(pv.x * (1.0f + sq));
                accS += pv.x;
            }
            {
                float2 a = e2[h.y], b = e2[t.y];
                float dx = a.x - b.x, dy = a.y - b.y;
                float sq = fmaf(dx, dx, dy * dy) * (SCALE * SCALE);
                accC += pv.y * __logf(pv.y * (1.0f + sq));
                accS += pv.y;
            }
            {
                float2 a = e2[h.z], b = e2[t.z];
                float dx = a.x - b.x, dy = a.y - b.y;
                float sq = fmaf(dx, dx, dy * dy) * (SCALE * SCALE);
                accC += pv.z * __logf(pv.z * (1.0f + sq));
                accS += pv.z;
            }
            {
                float2 a = e2[h.w], b = e2[t.w];
                float dx = a.x - b.x, dy = a.y - b.y;
                float sq = fmaf(dx, dx, dy * dy) * (SCALE * SCALE);
                accC += pv.w * __logf(pv.w * (1.0f + sq));
                accS += pv.w;
            }
        }
        for (int idx = (e4 << 2) + bid * THREADS + threadIdx.x; idx < e; idx += stride) {
            int h = heads[idx], t = tails[idx];
            float pv = p[idx];
            float2 a = e2[h], b = e2[t];
            float dx = a.x - b.x, dy = a.y - b.y;
            float sq = fmaf(dx, dx, dy * dy) * (SCALE * SCALE);
            accC += pv * __logf(pv * (1.0f + sq));
            accS += pv;
        }
#pragma unroll
        for (int off = 32; off > 0; off >>= 1) {
            accC += __shfl_down(accC, off, 64);
            accS += __shfl_down(accS, off, 64);
        }
        __shared__ float rc[THREADS / 64], rs[THREADS / 64];
        if (lane == 0) { rc[wid] = accC; rs[wid] = accS; }
        __syncthreads();
        if (threadIdx.x == 0) {
            float tc = 0.0f, ts = 0.0f;
#pragma unroll
            for (int w = 0; w < THREADS / 64; ++w) { tc += rc[w]; ts += rs[w]; }
            __hip_atomic_store(&pC[bid], (double)tc, __ATOMIC_RELAXED,
                               __HIP_MEMORY_SCOPE_AGENT);
            __hip_atomic_store(&pS[bid], (double)ts, __ATOMIC_RELAXED,
                               __HIP_MEMORY_SCOPE_AGENT);
            __hip_atomic_store(&flags[bid], MAGIC, __ATOMIC_RELEASE,
                               __HIP_MEMORY_SCOPE_AGENT);
        }
    } else {
        // ================= finalize (spin-wait producers, reduce, emit) =========
        const int nprod = EDGE_BLOCKS + nbBlocks;
        double lC = 0.0, lS = 0.0, lZ = 0.0;
        for (int b = threadIdx.x; b < nprod; b += THREADS) {
            while (__hip_atomic_load(&flags[b], __ATOMIC_ACQUIRE,
                                     __HIP_MEMORY_SCOPE_AGENT) != MAGIC)
                __builtin_amdgcn_s_sleep(8);
            if (b < EDGE_BLOCKS) {
                lC += __hip_atomic_load(&pC[b], __ATOMIC_RELAXED,
                                        __HIP_MEMORY_SCOPE_AGENT);
                lS += __hip_atomic_load(&pS[b], __ATOMIC_RELAXED,
                                        __HIP_MEMORY_SCOPE_AGENT);
            } else {
                lZ += __hip_atomic_load(&pZ[b - EDGE_BLOCKS], __ATOMIC_RELAXED,
                                        __HIP_MEMORY_SCOPE_AGENT);
            }
        }
#pragma unroll
        for (int off = 32; off > 0; off >>= 1) {
            lC += __shfl_down(lC, off, 64);
            lS += __shfl_down(lS, off, 64);
            lZ += __shfl_down(lZ, off, 64);
        }
        __shared__ double dred[3 * (THREADS / 64)];
        if (lane == 0) { dred[wid * 3] = lC; dred[wid * 3 + 1] = lS; dred[wid * 3 + 2] = lZ; }
        __syncthreads();
        if (threadIdx.x == 0) {
            double c = 0.0, sp = 0.0, z = 0.0;
#pragma unroll
            for (int w = 0; w < THREADS / 64; ++w) {
                c += dred[w * 3]; sp += dred[w * 3 + 1]; z += dred[w * 3 + 2];
            }
            z -= (double)n;  // remove self-pairs (each contributes ~1.0 exactly)
            out[0] = (float)(c + sp * log(z));
        }
    }
}

extern "C" void kernel_launch(void* const* d_in, const int* in_sizes, int n_in,
                              void* d_out, int out_size, void* d_ws, size_t ws_size,
                              hipStream_t stream) {
    const float* emb  = (const float*)d_in[0];
    const float* p    = (const float*)d_in[1];
    const int* heads  = (const int*)d_in[2];
    const int* tails  = (const int*)d_in[3];
    const int n = in_sizes[0] / 2;   // 32768 points (D=2)
    const int e = in_sizes[1];       // edge count

    const int nt = n / TJ;                    // 128
    const int nbBlocks = nt * (nt + 1) / 2;   // 8256 upper-triangle tiles

    double* pZ = (double*)d_ws;
    double* pC = pZ + nbBlocks;
    double* pS = pC + EDGE_BLOCKS;
    int* flags = (int*)(pS + EDGE_BLOCKS);

    const int total = EDGE_BLOCKS + nbBlocks + 1;
    fused_kernel<<<total, THREADS, 0, stream>>>(emb, p, heads, tails, e, n, nt,
                                                nbBlocks, pZ, pC, pS, flags,
                                                (float*)d_out);
}

// Round 4
// 144.543 us; speedup vs baseline: 1.9991x; 1.9991x over previous
//
#include <hip/hip_runtime.h>
#include <hip/hip_bf16.h>

#define SCALE 3.5f
#define TJ 512            // square tile size (points)
#define THREADS 256       // 4 waves per block
#define TPB 2             // tiles per Z-block (tail fix: grid fits in one round)
#define EDGE_BLOCKS 256
#define MAGIC 0x13572468  // != 0xAAAAAAAA poison

typedef __attribute__((ext_vector_type(8))) short short8;    // 8 bf16 = 4 VGPRs
typedef __attribute__((ext_vector_type(4))) short short4v;   // 4 bf16 = 2 VGPRs
typedef __attribute__((ext_vector_type(16))) float float16v; // 32x32 accumulator

// fp32 -> bf16 round-to-nearest-even (bit trick; inputs finite)
__device__ inline short bfh(float v) {
    union { float f; unsigned u; } x; x.f = v;
    unsigned r = (x.u + 0x7fffu + ((x.u >> 16) & 1u)) >> 16;
    return (short)r;
}
__device__ inline float bff(short s) {
    union { float f; unsigned u; } x; x.u = ((unsigned)(unsigned short)s) << 16;
    return x.f;
}

// LDS layout (short4v entries, 8B each):
//   A records: point i -> 16B [ahi,bhi,chi,1 | alo,blo,clo,0] at entries 2i,2i+1
//   BHI: [xh,yh,1,fh] per point ; BLO: [xl,yl,0,fl] per point
#define AREC 0      // 1024 entries (512 points * 16B)
#define BHI  1024   // 512 entries
#define BLO  1536   // 512 entries

// ws: double pZ[ZB] | double pC[EDGE_BLOCKS] | double pS[EDGE_BLOCKS]
//     | int flags[EDGE_BLOCKS + ZB]   (0xAA poison != MAGIC)

__global__ __launch_bounds__(THREADS, 4)
void fused_kernel(const float* __restrict__ emb,
                  const float* __restrict__ p,
                  const int* __restrict__ heads,
                  const int* __restrict__ tails,
                  int e, int n, int nt, int nbZ,
                  double* __restrict__ pZ,
                  double* __restrict__ pC,
                  double* __restrict__ pS,
                  int* __restrict__ flags,
                  float* __restrict__ out) {
    const int bid = blockIdx.x;
    const float2* e2 = (const float2*)emb;
    const int lane = threadIdx.x & 63, wid = threadIdx.x >> 6;

    if (bid >= EDGE_BLOCKS && bid < EDGE_BLOCKS + nbZ) {
        // ================= n-body tiles (Z) via 32x32x16 MFMA =================
        // t_ij = 1+|pi-pj|^2 = dot([ai,bi,ci,1],[xj,yj,1,fj]); scaled coords.
        // bf16 hi/lo split both sides; K=16 packs it exactly:
        //   k0-7 : A=[ahi,bhi,chi,1, alo,blo,clo,0]  B=[xh,yh,1,fh, xh,yh,1,fh]
        //   k8-15: A=      (same record)             B=[xl,yl,0,fl, xl,yl,0,fl]
        // -> all hi*hi, hi*lo, lo*hi, lo*lo cross terms, same product set as
        //    the previous K=32 3-quadrant scheme. Output layout irrelevant: we
        //    sum all 16 accumulator elements.
        const int z = bid - EDGE_BLOCKS;
        __shared__ __align__(16) short4v lds[2048];
        __shared__ float nred[THREADS / 64];
        const short ONE = (short)0x3F80;  // bf16 1.0
        const short8* A8 = (const short8*)lds;
        double zsum = 0.0;

#pragma unroll 1
        for (int half = 0; half < TPB; ++half) {
            const int b = z * TPB + half;   // tile id in [0, nt*(nt+1)/2)
            int ti = (int)((2.0f * nt + 1.0f -
                            sqrtf((float)((2 * nt + 1) * (2 * nt + 1) - 8 * b))) * 0.5f);
            while ((ti + 1) * nt - ((ti + 1) * ti) / 2 <= b) ++ti;
            while (ti * nt - (ti * (ti - 1)) / 2 > b) --ti;
            const int tj = ti + (b - (ti * nt - (ti * (ti - 1)) / 2));
            const int ibase = ti * TJ, jbase = tj * TJ;

            for (int k = threadIdx.x; k < TJ; k += THREADS) {
                float2 v = e2[ibase + k];
                float X = v.x * SCALE, Y = v.y * SCALE;
                float A = -2.0f * X, B = -2.0f * Y, C = fmaf(X, X, fmaf(Y, Y, 1.0f));
                short ah = bfh(A), bh = bfh(B), ch = bfh(C);
                lds[AREC + 2 * k]     = (short4v){ah, bh, ch, ONE};
                lds[AREC + 2 * k + 1] = (short4v){bfh(A - bff(ah)), bfh(B - bff(bh)),
                                                  bfh(C - bff(ch)), 0};
                float2 u = e2[jbase + k];
                float Xj = u.x * SCALE, Yj = u.y * SCALE, F = fmaf(Xj, Xj, Yj * Yj);
                short xh = bfh(Xj), yh = bfh(Yj), fh = bfh(F);
                lds[BHI + k] = (short4v){xh, yh, ONE, fh};
                lds[BLO + k] = (short4v){bfh(Xj - bff(xh)), bfh(Yj - bff(yh)), 0,
                                         bfh(F - bff(fh))};
            }
            __syncthreads();

            const int r = lane & 31;          // row/col within 32-group
            const int khalf = lane >> 5;      // 0: k0-7 (hi B), 1: k8-15 (lo B)

            // A-frags: wave wid owns i-rows wid*128 + rg*32 + r (same rec both k-halves)
            short8 afr0 = A8[wid * 128 + 0 * 32 + r];
            short8 afr1 = A8[wid * 128 + 1 * 32 + r];
            short8 afr2 = A8[wid * 128 + 2 * 32 + r];
            short8 afr3 = A8[wid * 128 + 3 * 32 + r];

            const float16v cz = {};
            float accv = 0.0f;
            for (int cg = 0; cg < TJ / 32; ++cg) {
                const int col = cg * 32 + r;
                short4v rec = lds[(khalf ? BLO : BHI) + col];
                short8 bfr = __builtin_shufflevector(rec, rec, 0, 1, 2, 3, 0, 1, 2, 3);
#pragma unroll
                for (int rg = 0; rg < 4; ++rg) {
                    short8 af = (rg == 0) ? afr0 : (rg == 1) ? afr1
                              : (rg == 2) ? afr2 : afr3;
                    float16v D = __builtin_amdgcn_mfma_f32_32x32x16_bf16(af, bfr,
                                                                         cz, 0, 0, 0);
#pragma unroll
                    for (int g = 0; g < 4; ++g) {
                        // 4-way rcp combine: sum 1/t = ((t2+t3)ab+(t0+t1)cd)/(ab*cd)
                        float t0 = D[4 * g], t1 = D[4 * g + 1];
                        float t2 = D[4 * g + 2], t3 = D[4 * g + 3];
                        float ab = t0 * t1, cd = t2 * t3;
                        float num = fmaf(t2 + t3, ab, (t0 + t1) * cd);
                        accv = fmaf(num, __builtin_amdgcn_rcpf(ab * cd), accv);
                    }
                }
            }
#pragma unroll
            for (int off = 32; off > 0; off >>= 1)
                accv += __shfl_down(accv, off, 64);

            if (lane == 0) nred[wid] = accv;
            __syncthreads();   // nred visible; also: all LDS reads done before restage
            if (threadIdx.x == 0) {
                float tot = 0.0f;
#pragma unroll
                for (int w = 0; w < THREADS / 64; ++w) tot += nred[w];
                zsum += (ti == tj ? 1.0 : 2.0) * (double)tot;
            }
        }
        if (threadIdx.x == 0) {
            __hip_atomic_store(&pZ[z], zsum, __ATOMIC_RELAXED, __HIP_MEMORY_SCOPE_AGENT);
            __hip_atomic_store(&flags[bid], MAGIC, __ATOMIC_RELEASE,
                               __HIP_MEMORY_SCOPE_AGENT);
        }
    } else if (bid < EDGE_BLOCKS) {
        // ================= edge (attractive + entropy) =================
        const int4* h4 = (const int4*)heads;
        const int4* t4 = (const int4*)tails;
        const float4* p4 = (const float4*)p;
        const int e4 = e >> 2;
        const int stride = EDGE_BLOCKS * THREADS;
        float accC = 0.0f, accS = 0.0f;
        for (int idx = bid * THREADS + threadIdx.x; idx < e4; idx += stride) {
            int4 h = h4[idx];
            int4 t = t4[idx];
            float4 pv = p4[idx];
            {
                float2 a = e2[h.x], b = e2[t.x];
                float dx = a.x - b.x, dy = a.y - b.y;
                float sq = fmaf(dx, dx, dy * dy) * (SCALE * SCALE);
                accC += pv.x * __logf(pv.x * (1.0f + sq));
                accS += pv.x;
            }
            {
                float2 a = e2[h.y], b = e2[t.y];
                float dx = a.x - b.x, dy = a.y - b.y;
                float sq = fmaf(dx, dx, dy * dy) * (SCALE * SCALE);
                accC += pv.y * __logf(pv.y * (1.0f + sq));
                accS += pv.y;
            }
            {
                float2 a = e2[h.z], b = e2[t.z];
                float dx = a.x - b.x, dy = a.y - b.y;
                float sq = fmaf(dx, dx, dy * dy) * (SCALE * SCALE);
                accC += pv.z * __logf(pv.z * (1.0f + sq));
                accS += pv.z;
            }
            {
                float2 a = e2[h.w], b = e2[t.w];
                float dx = a.x - b.x, dy = a.y - b.y;
                float sq = fmaf(dx, dx, dy * dy) * (SCALE * SCALE);
                accC += pv.w * __logf(pv.w * (1.0f + sq));
                accS += pv.w;
            }
        }
        for (int idx = (e4 << 2) + bid * THREADS + threadIdx.x; idx < e; idx += stride) {
            int h = heads[idx], t = tails[idx];
            float pv = p[idx];
            float2 a = e2[h], b = e2[t];
            float dx = a.x - b.x, dy = a.y - b.y;
            float sq = fmaf(dx, dx, dy * dy) * (SCALE * SCALE);
            accC += pv * __logf(pv * (1.0f + sq));
            accS += pv;
        }
#pragma unroll
        for (int off = 32; off > 0; off >>= 1) {
            accC += __shfl_down(accC, off, 64);
            accS += __shfl_down(accS, off, 64);
        }
        __shared__ float rc[THREADS / 64], rs[THREADS / 64];
        if (lane == 0) { rc[wid] = accC; rs[wid] = accS; }
        __syncthreads();
        if (threadIdx.x == 0) {
            float tc = 0.0f, ts = 0.0f;
#pragma unroll
            for (int w = 0; w < THREADS / 64; ++w) { tc += rc[w]; ts += rs[w]; }
            __hip_atomic_store(&pC[bid], (double)tc, __ATOMIC_RELAXED,
                               __HIP_MEMORY_SCOPE_AGENT);
            __hip_atomic_store(&pS[bid], (double)ts, __ATOMIC_RELAXED,
                               __HIP_MEMORY_SCOPE_AGENT);
            __hip_atomic_store(&flags[bid], MAGIC, __ATOMIC_RELEASE,
                               __HIP_MEMORY_SCOPE_AGENT);
        }
    } else {
        // ================= finalize (spin-wait producers, reduce, emit) =========
        const int nprod = EDGE_BLOCKS + nbZ;
        double lC = 0.0, lS = 0.0, lZ = 0.0;
        for (int b = threadIdx.x; b < nprod; b += THREADS) {
            while (__hip_atomic_load(&flags[b], __ATOMIC_ACQUIRE,
                                     __HIP_MEMORY_SCOPE_AGENT) != MAGIC)
                __builtin_amdgcn_s_sleep(8);
            if (b < EDGE_BLOCKS) {
                lC += __hip_atomic_load(&pC[b], __ATOMIC_RELAXED,
                                        __HIP_MEMORY_SCOPE_AGENT);
                lS += __hip_atomic_load(&pS[b], __ATOMIC_RELAXED,
                                        __HIP_MEMORY_SCOPE_AGENT);
            } else {
                lZ += __hip_atomic_load(&pZ[b - EDGE_BLOCKS], __ATOMIC_RELAXED,
                                        __HIP_MEMORY_SCOPE_AGENT);
            }
        }
#pragma unroll
        for (int off = 32; off > 0; off >>= 1) {
            lC += __shfl_down(lC, off, 64);
            lS += __shfl_down(lS, off, 64);
            lZ += __shfl_down(lZ, off, 64);
        }
        __shared__ double dred[3 * (THREADS / 64)];
        if (lane == 0) { dred[wid * 3] = lC; dred[wid * 3 + 1] = lS; dred[wid * 3 + 2] = lZ; }
        __syncthreads();
        if (threadIdx.x == 0) {
            double c = 0.0, sp = 0.0, zt = 0.0;
#pragma unroll
            for (int w = 0; w < THREADS / 64; ++w) {
                c += dred[w * 3]; sp += dred[w * 3 + 1]; zt += dred[w * 3 + 2];
            }
            zt -= (double)n;  // remove self-pairs (each contributes ~1.0 exactly)
            out[0] = (float)(c + sp * log(zt));
        }
    }
}

extern "C" void kernel_launch(void* const* d_in, const int* in_sizes, int n_in,
                              void* d_out, int out_size, void* d_ws, size_t ws_size,
                              hipStream_t stream) {
    const float* emb  = (const float*)d_in[0];
    const float* p    = (const float*)d_in[1];
    const int* heads  = (const int*)d_in[2];
    const int* tails  = (const int*)d_in[3];
    const int n = in_sizes[0] / 2;   // 32768 points (D=2)
    const int e = in_sizes[1];       // edge count

    const int nt = n / TJ;                    // 64 tiles per side
    const int nbTiles = nt * (nt + 1) / 2;    // 2080 upper-triangle tiles
    const int nbZ = nbTiles / TPB;            // 1040 Z-blocks (2 tiles each)

    double* pZ = (double*)d_ws;
    double* pC = pZ + nbZ;
    double* pS = pC + EDGE_BLOCKS;
    int* flags = (int*)(pS + EDGE_BLOCKS);

    const int total = EDGE_BLOCKS + nbZ + 1;  // 1297 blocks -> single round
    fused_kernel<<<total, THREADS, 0, stream>>>(emb, p, heads, tails, e, n, nt,
                                                nbZ, pZ, pC, pS, flags,
                                                (float*)d_out);
}

// Round 5
// 139.167 us; speedup vs baseline: 2.0763x; 1.0386x over previous
//
#include <hip/hip_runtime.h>
#include <hip/hip_bf16.h>

#define SCALE 3.5f
#define TJ 512            // tile rows (A side)
#define HC 256            // half-tile cols (B side) -> 4160 steal items
#define THREADS 256       // 4 waves per block
#define EDGE_BLOCKS 256
#define GRID_BLOCKS 2048  // 8 blocks/CU * 256 CUs: full residency, single round
#define MAGIC 0x13572468  // != 0xAAAAAAAA poison
#define POISON ((int)0xAAAAAAAA)

typedef __attribute__((ext_vector_type(8))) short short8;    // 8 bf16 = 4 VGPRs
typedef __attribute__((ext_vector_type(4))) short short4v;   // 4 bf16 = 2 VGPRs
typedef __attribute__((ext_vector_type(16))) float float16v; // 32x32 accumulator

// fp32 -> bf16 round-to-nearest-even (bit trick; inputs finite)
__device__ inline short bfh(float v) {
    union { float f; unsigned u; } x; x.f = v;
    unsigned r = (x.u + 0x7fffu + ((x.u >> 16) & 1u)) >> 16;
    return (short)r;
}
__device__ inline float bff(short s) {
    union { float f; unsigned u; } x; x.u = ((unsigned)(unsigned short)s) << 16;
    return x.f;
}

// LDS layout (short4v entries, 8B each):
//   A records: point i -> 16B [ahi,bhi,chi,1 | alo,blo,clo,0] at entries 2i,2i+1
//   BHI: [xh,yh,1,fh] per col point ; BLO: [xl,yl,0,fl]
#define AREC 0      // 1024 entries (512 rows * 16B)
#define BHI  1024   // 256 entries
#define BLO  1280   // 256 entries

// ws: double pZ[nbW] | double pC[EDGE_BLOCKS] | double pS[EDGE_BLOCKS]
//     | int flags[EDGE_BLOCKS + nbW]  (0xAA poison != MAGIC) | int ctr[1]
// ctr is POISON-relative (harness re-poisons ws before every run/replay).

__global__ __launch_bounds__(THREADS, 4)
void fused_kernel(const float* __restrict__ emb,
                  const float* __restrict__ p,
                  const int* __restrict__ heads,
                  const int* __restrict__ tails,
                  int e, int n, int nt, int nbW, int nItems,
                  double* __restrict__ pZ,
                  double* __restrict__ pC,
                  double* __restrict__ pS,
                  int* __restrict__ flags,
                  int* __restrict__ ctr,
                  float* __restrict__ out) {
    const int bid = blockIdx.x;
    const float2* e2 = (const float2*)emb;
    const int lane = threadIdx.x & 63, wid = threadIdx.x >> 6;

    if (bid >= EDGE_BLOCKS && bid < EDGE_BLOCKS + nbW) {
        // ========== n-body (Z): work-stealing half-tiles via 32x32x16 MFMA ==========
        // t_ij = 1+|pi-pj|^2 = dot([ai,bi,ci,1],[xj,yj,1,fj]); scaled coords.
        // bf16 hi/lo split both sides; K=16 packs all 4 cross-products:
        //   k0-7 : A=[ahi,bhi,chi,1, alo,blo,clo,0]  B=[xh,yh,1,fh, xh,yh,1,fh]
        //   k8-15: A=      (same record)             B=[xl,yl,0,fl, xl,yl,0,fl]
        // Output layout irrelevant: we sum all 16 accumulator elements.
        const int widx = bid - EDGE_BLOCKS;
        __shared__ __align__(16) short4v lds[1536];
        __shared__ float nred[THREADS / 64];
        __shared__ int sh_item;
        const short ONE = (short)0x3F80;  // bf16 1.0
        const short8* A8 = (const short8*)lds;
        double zsum = 0.0;

        int item = widx;  // static first item (no t=0 atomic burst); then steal
        while (item < nItems) {
            const int b = item >> 1, half = item & 1;
            int ti = (int)((2.0f * nt + 1.0f -
                            sqrtf((float)((2 * nt + 1) * (2 * nt + 1) - 8 * b))) * 0.5f);
            while ((ti + 1) * nt - ((ti + 1) * ti) / 2 <= b) ++ti;
            while (ti * nt - (ti * (ti - 1)) / 2 > b) --ti;
            const int tj = ti + (b - (ti * nt - (ti * (ti - 1)) / 2));
            const int ibase = ti * TJ, jbase = tj * TJ + half * HC;

            for (int k = threadIdx.x; k < TJ; k += THREADS) {
                float2 v = e2[ibase + k];
                float X = v.x * SCALE, Y = v.y * SCALE;
                float A = -2.0f * X, B = -2.0f * Y, C = fmaf(X, X, fmaf(Y, Y, 1.0f));
                short ah = bfh(A), bh = bfh(B), ch = bfh(C);
                lds[AREC + 2 * k]     = (short4v){ah, bh, ch, ONE};
                lds[AREC + 2 * k + 1] = (short4v){bfh(A - bff(ah)), bfh(B - bff(bh)),
                                                  bfh(C - bff(ch)), 0};
            }
            {
                const int k = threadIdx.x;  // THREADS == HC
                float2 u = e2[jbase + k];
                float Xj = u.x * SCALE, Yj = u.y * SCALE, F = fmaf(Xj, Xj, Yj * Yj);
                short xh = bfh(Xj), yh = bfh(Yj), fh = bfh(F);
                lds[BHI + k] = (short4v){xh, yh, ONE, fh};
                lds[BLO + k] = (short4v){bfh(Xj - bff(xh)), bfh(Yj - bff(yh)), 0,
                                         bfh(F - bff(fh))};
            }
            __syncthreads();

            const int r = lane & 31;          // row/col within 32-group
            const int khalf = lane >> 5;      // 0: k0-7 (hi B), 1: k8-15 (lo B)

            short8 afr[4];
#pragma unroll
            for (int rg = 0; rg < 4; ++rg)
                afr[rg] = A8[wid * 128 + rg * 32 + r];

            const float16v cz = {};
            float a0 = 0.0f, a1 = 0.0f, a2 = 0.0f, a3 = 0.0f;
            for (int cg = 0; cg < HC / 32; ++cg) {
                const int col = cg * 32 + r;
                short4v rec = lds[(khalf ? BLO : BHI) + col];
                short8 bfr = __builtin_shufflevector(rec, rec, 0, 1, 2, 3, 0, 1, 2, 3);
#pragma unroll
                for (int rg = 0; rg < 4; ++rg) {
                    float16v D = __builtin_amdgcn_mfma_f32_32x32x16_bf16(afr[rg], bfr,
                                                                         cz, 0, 0, 0);
                    // 4-way rcp combine per group: sum 1/t = ((t2+t3)ab+(t0+t1)cd)/(ab cd)
#define COMB(g, acc)                                                        \
                    {                                                       \
                        float t0 = D[4 * g], t1 = D[4 * g + 1];             \
                        float t2 = D[4 * g + 2], t3 = D[4 * g + 3];         \
                        float ab = t0 * t1, cd = t2 * t3;                   \
                        float num = fmaf(t2 + t3, ab, (t0 + t1) * cd);      \
                        acc = fmaf(num, __builtin_amdgcn_rcpf(ab * cd), acc); \
                    }
                    COMB(0, a0) COMB(1, a1) COMB(2, a2) COMB(3, a3)
#undef COMB
                }
            }
            float accv = (a0 + a1) + (a2 + a3);
#pragma unroll
            for (int off = 32; off > 0; off >>= 1)
                accv += __shfl_down(accv, off, 64);

            if (lane == 0) nred[wid] = accv;
            __syncthreads();
            if (threadIdx.x == 0) {
                float tot = 0.0f;
#pragma unroll
                for (int w = 0; w < THREADS / 64; ++w) tot += nred[w];
                zsum += (ti == tj ? 1.0 : 2.0) * (double)tot;
                sh_item = __hip_atomic_fetch_add(&ctr[0], 1, __ATOMIC_RELAXED,
                                                 __HIP_MEMORY_SCOPE_AGENT)
                          - POISON + nbW;   // stolen items start after static ones
            }
            __syncthreads();   // sh_item visible; LDS reads done before restage
            item = sh_item;
        }
        if (threadIdx.x == 0) {
            __hip_atomic_store(&pZ[widx], zsum, __ATOMIC_RELAXED,
                               __HIP_MEMORY_SCOPE_AGENT);
            __hip_atomic_store(&flags[bid], MAGIC, __ATOMIC_RELEASE,
                               __HIP_MEMORY_SCOPE_AGENT);
        }
    } else if (bid < EDGE_BLOCKS) {
        // ================= edge (attractive + entropy) =================
        const int4* h4 = (const int4*)heads;
        const int4* t4 = (const int4*)tails;
        const float4* p4 = (const float4*)p;
        const int e4 = e >> 2;
        const int stride = EDGE_BLOCKS * THREADS;
        float accC = 0.0f, accS = 0.0f;
        for (int idx = bid * THREADS + threadIdx.x; idx < e4; idx += stride) {
            int4 h = h4[idx];
            int4 t = t4[idx];
            float4 pv = p4[idx];
            {
                float2 a = e2[h.x], b = e2[t.x];
                float dx = a.x - b.x, dy = a.y - b.y;
                float sq = fmaf(dx, dx, dy * dy) * (SCALE * SCALE);
                accC += pv.x * __logf(pv.x * (1.0f + sq));
                accS += pv.x;
            }
            {
                float2 a = e2[h.y], b = e2[t.y];
                float dx = a.x - b.x, dy = a.y - b.y;
                float sq = fmaf(dx, dx, dy * dy) * (SCALE * SCALE);
                accC += pv.y * __logf(pv.y * (1.0f + sq));
                accS += pv.y;
            }
            {
                float2 a = e2[h.z], b = e2[t.z];
                float dx = a.x - b.x, dy = a.y - b.y;
                float sq = fmaf(dx, dx, dy * dy) * (SCALE * SCALE);
                accC += pv.z * __logf(pv.z * (1.0f + sq));
                accS += pv.z;
            }
            {
                float2 a = e2[h.w], b = e2[t.w];
                float dx = a.x - b.x, dy = a.y - b.y;
                float sq = fmaf(dx, dx, dy * dy) * (SCALE * SCALE);
                accC += pv.w * __logf(pv.w * (1.0f + sq));
                accS += pv.w;
            }
        }
        for (int idx = (e4 << 2) + bid * THREADS + threadIdx.x; idx < e; idx += stride) {
            int h = heads[idx], t = tails[idx];
            float pv = p[idx];
            float2 a = e2[h], b = e2[t];
            float dx = a.x - b.x, dy = a.y - b.y;
            float sq = fmaf(dx, dx, dy * dy) * (SCALE * SCALE);
            accC += pv * __logf(pv * (1.0f + sq));
            accS += pv;
        }
#pragma unroll
        for (int off = 32; off > 0; off >>= 1) {
            accC += __shfl_down(accC, off, 64);
            accS += __shfl_down(accS, off, 64);
        }
        __shared__ float rc[THREADS / 64], rs[THREADS / 64];
        if (lane == 0) { rc[wid] = accC; rs[wid] = accS; }
        __syncthreads();
        if (threadIdx.x == 0) {
            float tc = 0.0f, ts = 0.0f;
#pragma unroll
            for (int w = 0; w < THREADS / 64; ++w) { tc += rc[w]; ts += rs[w]; }
            __hip_atomic_store(&pC[bid], (double)tc, __ATOMIC_RELAXED,
                               __HIP_MEMORY_SCOPE_AGENT);
            __hip_atomic_store(&pS[bid], (double)ts, __ATOMIC_RELAXED,
                               __HIP_MEMORY_SCOPE_AGENT);
            __hip_atomic_store(&flags[bid], MAGIC, __ATOMIC_RELEASE,
                               __HIP_MEMORY_SCOPE_AGENT);
        }
    } else {
        // ================= finalize (spin-wait producers, reduce, emit) =========
        const int nprod = EDGE_BLOCKS + nbW;
        double lC = 0.0, lS = 0.0, lZ = 0.0;
        for (int b = threadIdx.x; b < nprod; b += THREADS) {
            while (__hip_atomic_load(&flags[b], __ATOMIC_ACQUIRE,
                                     __HIP_MEMORY_SCOPE_AGENT) != MAGIC)
                __builtin_amdgcn_s_sleep(8);
            if (b < EDGE_BLOCKS) {
                lC += __hip_atomic_load(&pC[b], __ATOMIC_RELAXED,
                                        __HIP_MEMORY_SCOPE_AGENT);
                lS += __hip_atomic_load(&pS[b], __ATOMIC_RELAXED,
                                        __HIP_MEMORY_SCOPE_AGENT);
            } else {
                lZ += __hip_atomic_load(&pZ[b - EDGE_BLOCKS], __ATOMIC_RELAXED,
                                        __HIP_MEMORY_SCOPE_AGENT);
            }
        }
#pragma unroll
        for (int off = 32; off > 0; off >>= 1) {
            lC += __shfl_down(lC, off, 64);
            lS += __shfl_down(lS, off, 64);
            lZ += __shfl_down(lZ, off, 64);
        }
        __shared__ double dred[3 * (THREADS / 64)];
        if (lane == 0) { dred[wid * 3] = lC; dred[wid * 3 + 1] = lS; dred[wid * 3 + 2] = lZ; }
        __syncthreads();
        if (threadIdx.x == 0) {
            double c = 0.0, sp = 0.0, zt = 0.0;
#pragma unroll
            for (int w = 0; w < THREADS / 64; ++w) {
                c += dred[w * 3]; sp += dred[w * 3 + 1]; zt += dred[w * 3 + 2];
            }
            zt -= (double)n;  // remove self-pairs (each contributes ~1.0 exactly)
            out[0] = (float)(c + sp * log(zt));
        }
    }
}

extern "C" void kernel_launch(void* const* d_in, const int* in_sizes, int n_in,
                              void* d_out, int out_size, void* d_ws, size_t ws_size,
                              hipStream_t stream) {
    const float* emb  = (const float*)d_in[0];
    const float* p    = (const float*)d_in[1];
    const int* heads  = (const int*)d_in[2];
    const int* tails  = (const int*)d_in[3];
    const int n = in_sizes[0] / 2;   // 32768 points (D=2)
    const int e = in_sizes[1];       // edge count

    const int nt = n / TJ;                    // 64 tiles per side
    const int nbTiles = nt * (nt + 1) / 2;    // 2080 upper-triangle tiles
    const int nItems = nbTiles * (TJ / HC);   // 4160 half-tiles (steal quanta)
    const int nbW = GRID_BLOCKS - EDGE_BLOCKS - 1;  // 1791 Z-workers

    double* pZ = (double*)d_ws;
    double* pC = pZ + nbW;
    double* pS = pC + EDGE_BLOCKS;
    int* flags = (int*)(pS + EDGE_BLOCKS);
    int* ctr = flags + (EDGE_BLOCKS + nbW);

    fused_kernel<<<GRID_BLOCKS, THREADS, 0, stream>>>(emb, p, heads, tails, e, n,
                                                      nt, nbW, nItems, pZ, pC, pS,
                                                      flags, ctr, (float*)d_out);
}